// Round 2
// baseline (252.119 us; speedup 1.0000x reference)
//
#include <hip/hip_runtime.h>

#define DI __device__ __forceinline__

using bf16x8 = __attribute__((ext_vector_type(8))) __bf16;
using f32x4  = __attribute__((ext_vector_type(4))) float;

typedef unsigned short u16;
typedef unsigned int   u32;

static constexpr float SM_SCALE = 0.0625f;     // 1/sqrt(FEAT=256)
static constexpr float LAMBD    = 1.0f / 512.0f;

// ---------------- workspace byte offsets ----------------
static constexpr size_t OFF_THETA  = 0;         // bf16 [256][512]
static constexpr size_t OFF_PROTOT = 262144;    // bf16 [512][256]  (proto^T)
static constexpr size_t OFF_PROTO  = 524288;    // bf16 [256][512]
static constexpr size_t OFF_FC1    = 786432;    // bf16 [512][512]
static constexpr size_t OFF_FC2    = 1310720;   // bf16 [512][512]
static constexpr size_t OFF_O      = 1835008;   // bf16 [512][256]
static constexpr size_t OFF_PSUM   = 2097152;   // f32 [512 ch][512 blk]
static constexpr size_t OFF_PSQ    = 3145728;   // f32 [512 ch][512 blk]
static constexpr size_t OFF_AFF    = 4194304;   // f32 [512][2] (scale, shift)

// ---------------- LDS layout (mega kernel) ----------------
static constexpr int ABUF  = 0;        // 64 KiB: current A-operand [64 rows][K] bf16, swizzled
static constexpr int BBUF  = 65536;    // 64 KiB: weight slab [cols][64 k] bf16, swizzled
static constexpr int RROFF = 131072;   // 3 x [64][8] f32 per-wave row partials
static constexpr int RFOFF = 137216;   // 3 x [64]    f32 per-row finals
static constexpr int SMEM_BYTES = 137984;

DI u16 f2b(float f) {
  union { float f; u32 u; } c; c.f = f;
  u32 r = c.u + 0x7FFFu + ((c.u >> 16) & 1u);   // RNE
  return (u16)(r >> 16);
}

// ---------------- prep: weights f32 -> bf16 (+ proto transpose) ----------------
__global__ __launch_bounds__(256) void prep_kernel(
    const float* __restrict__ theta, const float* __restrict__ proto,
    const float* __restrict__ fc1,   const float* __restrict__ fc2,
    const float* __restrict__ ow,    char* __restrict__ ws)
{
  u16* w_theta  = (u16*)(ws + OFF_THETA);
  u16* w_protoT = (u16*)(ws + OFF_PROTOT);
  u16* w_proto  = (u16*)(ws + OFF_PROTO);
  u16* w_fc1    = (u16*)(ws + OFF_FC1);
  u16* w_fc2    = (u16*)(ws + OFF_FC2);
  u16* w_o      = (u16*)(ws + OFF_O);
  for (int i = blockIdx.x * blockDim.x + threadIdx.x; i < 1048576;
       i += gridDim.x * blockDim.x) {
    if (i < 131072) { w_theta[i] = f2b(theta[i]); }
    else if (i < 262144) { int j = i - 131072; int k = j >> 8, f = j & 255;
                           w_protoT[j] = f2b(proto[f * 512 + k]); }
    else if (i < 393216) { int j = i - 262144; w_proto[j] = f2b(proto[j]); }
    else if (i < 655360) { int j = i - 393216; w_fc1[j] = f2b(fc1[j]); }
    else if (i < 917504) { int j = i - 655360; w_fc2[j] = f2b(fc2[j]); }
    else                 { int j = i - 917504; w_o[j]   = f2b(ow[j]); }
  }
}

// ---------------- mega-kernel helpers ----------------
// A/B-operand LDS read: row-major [row][k] bf16, byte-swizzle ^((row&7)<<4)
DI bf16x8 ld_a(const char* base, int row, int pitch, int kbyte) {
  return *(const bf16x8*)(base + row * pitch + (kbyte ^ ((row & 7) << 4)));
}

// stage a [cols][64 k] weight slab from global bf16 [col][KTOT] into BBUF
template<int KTOT, int NB>
DI void stage_w(char* bbuf, const u16* __restrict__ gsrc, int kk, int tid) {
  #pragma unroll
  for (int q = 0; q < NB / 64; ++q) {
    const int idx = q * 512 + tid;
    const int col = idx >> 3;
    const int kl  = idx & 7;
    bf16x8 v = *(const bf16x8*)(gsrc + (size_t)col * KTOT + kk * 64 + kl * 8);
    *(bf16x8*)(bbuf + col * 128 + ((kl * 16) ^ ((col & 7) << 4))) = v;
  }
}

// pixel-rows GEMM: acc[4 rowtiles][CT coltiles] += A_lds[64][KTOT] @ W[KTOT][NB]
template<int KTOT, int NB, int CT, int PITCH>
DI void gemm_px(f32x4 (&acc)[4][CT], const char* abuf, char* bbuf,
                const u16* __restrict__ wsrc, int w, int l, int tid) {
  for (int kk = 0; kk < KTOT / 64; ++kk) {
    stage_w<KTOT, NB>(bbuf, wsrc, kk, tid);
    __syncthreads();
    #pragma unroll
    for (int ks = 0; ks < 2; ++ks) {
      const int kbs = ks * 64 + (l >> 4) * 16;
      bf16x8 af[4];
      #pragma unroll
      for (int r0 = 0; r0 < 4; ++r0)
        af[r0] = ld_a(abuf, r0 * 16 + (l & 15), PITCH, kk * 128 + kbs);
      #pragma unroll
      for (int j = 0; j < CT; ++j) {
        bf16x8 bf = ld_a(bbuf, (w + 8 * j) * 16 + (l & 15), 128, kbs);
        #pragma unroll
        for (int r0 = 0; r0 < 4; ++r0)
          acc[r0][j] = __builtin_amdgcn_mfma_f32_16x16x32_bf16(af[r0], bf, acc[r0][j], 0, 0, 0);
      }
    }
    __syncthreads();
  }
}

// store fragment tiles to ABUF as bf16 [row][col], swizzled; rows=pixels
template<int CT, int PITCH>
DI void store_px(char* abuf, const f32x4 (&v)[4][CT], int w, int l) {
  #pragma unroll
  for (int j = 0; j < CT; ++j) {
    const int col = (w + 8 * j) * 16 + (l & 15);
    #pragma unroll
    for (int r0 = 0; r0 < 4; ++r0)
      #pragma unroll
      for (int rr = 0; rr < 4; ++rr) {
        const int row = r0 * 16 + (l >> 4) * 4 + rr;
        *(u16*)(abuf + row * PITCH + ((col * 2) ^ ((row & 7) << 4))) = f2b(v[r0][j][rr]);
      }
  }
}

template<bool ISMAX>
DI float red16(float v) {
  #pragma unroll
  for (int s = 1; s < 16; s <<= 1) {
    float o = __shfl_xor(v, s, 64);
    v = ISMAX ? fmaxf(v, o) : (v + o);
  }
  return v;
}

// cross-wave per-row reduction: part (already reduced over this wave's 16 lanes
// and its col-tiles) -> full per-row result in res
template<bool ISMAX>
DI void row_round(char* smem, int round, float (&part)[4][4], float (&res)[4][4],
                  int w, int l, int tid) {
  float* rrb = (float*)(smem + RROFF + round * 2048);
  float* rfb = (float*)(smem + RFOFF + round * 256);
  const int g = l >> 4;
  if ((l & 15) == 0) {
    #pragma unroll
    for (int r0 = 0; r0 < 4; ++r0)
      #pragma unroll
      for (int rr = 0; rr < 4; ++rr)
        rrb[(r0 * 16 + g * 4 + rr) * 8 + w] = part[r0][rr];
  }
  __syncthreads();
  if (tid < 64) {
    float m = ISMAX ? -3.0e38f : 0.0f;
    #pragma unroll
    for (int q = 0; q < 8; ++q) {
      float v = rrb[tid * 8 + q];
      m = ISMAX ? fmaxf(m, v) : (m + v);
    }
    rfb[tid] = m;
  }
  __syncthreads();
  #pragma unroll
  for (int r0 = 0; r0 < 4; ++r0)
    #pragma unroll
    for (int rr = 0; rr < 4; ++rr)
      res[r0][rr] = rfb[r0 * 16 + g * 4 + rr];
}

// ---------------- mega: full fused chain for 64 pixel-rows per block ----------------
__global__ __launch_bounds__(512, 2) void mega_kernel(
    const float* __restrict__ x, const char* __restrict__ ws,
    const float* __restrict__ fc1b, const float* __restrict__ fc2b,
    const float* __restrict__ gammap, float* __restrict__ out,
    float* __restrict__ psum, float* __restrict__ psq)
{
  extern __shared__ __align__(16) char smem[];
  const int tid = threadIdx.x;
  const int w   = tid >> 6;
  const int l   = tid & 63;
  const int bid = blockIdx.x;
  const int m0  = bid << 6;
  const int n   = m0 >> 12;      // image index (4096 pixels per image)
  const int p0  = m0 & 4095;     // pixel offset inside image

  const u16* w_theta  = (const u16*)(ws + OFF_THETA);
  const u16* w_protoT = (const u16*)(ws + OFF_PROTOT);
  const u16* w_proto  = (const u16*)(ws + OFF_PROTO);
  const u16* w_fc1    = (const u16*)(ws + OFF_FC1);
  const u16* w_fc2    = (const u16*)(ws + OFF_FC2);
  const u16* w_o      = (const u16*)(ws + OFF_O);

  char* abuf = smem + ABUF;
  char* bbuf = smem + BBUF;

  // ---- load X tile: global [c][p] f32 -> LDS [row=p][k=c] bf16, swizzled
  #pragma unroll
  for (int q = 0; q < 8; ++q) {
    const int cidx = q * 64 + (tid >> 3);
    const int j0   = (tid & 7) * 8;
    const float* xp = x + ((size_t)(n * 512 + cidx)) * 4096 + (size_t)(p0 + j0);
    f32x4 v0 = *(const f32x4*)xp;
    f32x4 v1 = *(const f32x4*)(xp + 4);
    #pragma unroll
    for (int i = 0; i < 8; ++i) {
      const float f = (i < 4) ? v0[i] : v1[i - 4];
      const int row = j0 + i;
      *(u16*)(abuf + row * 1024 + ((cidx * 2) ^ ((row & 7) << 4))) = f2b(f);
    }
  }
  // (first gemm's stage barrier orders these writes before any MFMA read)

  const f32x4 zz = {0.f, 0.f, 0.f, 0.f};

  // ---- stage A: Q[64][256] = X[64][512] @ theta^T
  f32x4 accq[4][2];
  #pragma unroll
  for (int a = 0; a < 4; ++a) { accq[a][0] = zz; accq[a][1] = zz; }
  gemm_px<512, 256, 2, 1024>(accq, abuf, bbuf, w_theta, w, l, tid);
  store_px<2, 512>(abuf, accq, w, l);          // Q, pitch 512 (K=256 next)

  // ---- stage B: logits[64][512] = Q @ proto (via proto^T operand)
  f32x4 lac[4][4];
  #pragma unroll
  for (int a = 0; a < 4; ++a)
    #pragma unroll
    for (int b = 0; b < 4; ++b) lac[a][b] = zz;
  gemm_px<256, 512, 4, 512>(lac, abuf, bbuf, w_protoT, w, l, tid);

  // ---- stage C: softmax(logits*scale) -> hard-shrink -> L1 renorm (all f32)
  {
    float part[4][4], rres[4][4];
    #pragma unroll
    for (int r0 = 0; r0 < 4; ++r0)
      #pragma unroll
      for (int rr = 0; rr < 4; ++rr) {
        float m2 = lac[r0][0][rr];
        #pragma unroll
        for (int j = 1; j < 4; ++j) m2 = fmaxf(m2, lac[r0][j][rr]);
        part[r0][rr] = red16<true>(m2);
      }
    row_round<true>(smem, 0, part, rres, w, l, tid);
    #pragma unroll
    for (int r0 = 0; r0 < 4; ++r0)
      #pragma unroll
      for (int rr = 0; rr < 4; ++rr) {
        const float mr = rres[r0][rr];
        float s2 = 0.f;
        #pragma unroll
        for (int j = 0; j < 4; ++j) {
          float e = __expf((lac[r0][j][rr] - mr) * SM_SCALE);
          lac[r0][j][rr] = e;
          s2 += e;
        }
        part[r0][rr] = red16<false>(s2);
      }
    row_round<false>(smem, 1, part, rres, w, l, tid);
    #pragma unroll
    for (int r0 = 0; r0 < 4; ++r0)
      #pragma unroll
      for (int rr = 0; rr < 4; ++rr) {
        const float rinv = 1.0f / rres[r0][rr];
        float s2 = 0.f;
        #pragma unroll
        for (int j = 0; j < 4; ++j) {
          float s = lac[r0][j][rr] * rinv;
          float t = s - LAMBD;
          float a = __fdividef(fmaxf(t, 0.f) * s, fabsf(t) + 1e-12f);
          lac[r0][j][rr] = a;
          s2 += a;
        }
        part[r0][rr] = red16<false>(s2);
      }
    row_round<false>(smem, 2, part, rres, w, l, tid);
    #pragma unroll
    for (int r0 = 0; r0 < 4; ++r0)
      #pragma unroll
      for (int rr = 0; rr < 4; ++rr) {
        const float rinv = 1.0f / (rres[r0][rr] + 1e-12f);
        #pragma unroll
        for (int j = 0; j < 4; ++j) lac[r0][j][rr] *= rinv;
      }
  }
  store_px<4, 1024>(abuf, lac, w, l);          // attn (A1), pitch 1024

  // ---- stage D: R = relu(A1 @ fc1^T + b1)
  f32x4 accd[4][4];
  #pragma unroll
  for (int a = 0; a < 4; ++a)
    #pragma unroll
    for (int b = 0; b < 4; ++b) accd[a][b] = zz;
  gemm_px<512, 512, 4, 1024>(accd, abuf, bbuf, w_fc1, w, l, tid);
  #pragma unroll
  for (int j = 0; j < 4; ++j) {
    const float b1 = fc1b[(w + 8 * j) * 16 + (l & 15)];
    #pragma unroll
    for (int r0 = 0; r0 < 4; ++r0)
      #pragma unroll
      for (int rr = 0; rr < 4; ++rr)
        accd[r0][j][rr] = fmaxf(accd[r0][j][rr] + b1, 0.f);
  }
  store_px<4, 1024>(abuf, accd, w, l);         // R, pitch 1024

  // ---- stage E: A2 = A1 + R @ fc2^T + b2  (attn regs are the accumulator)
  #pragma unroll
  for (int j = 0; j < 4; ++j) {
    const float b2 = fc2b[(w + 8 * j) * 16 + (l & 15)];
    #pragma unroll
    for (int r0 = 0; r0 < 4; ++r0)
      #pragma unroll
      for (int rr = 0; rr < 4; ++rr)
        lac[r0][j][rr] += b2;
  }
  gemm_px<512, 512, 4, 1024>(lac, abuf, bbuf, w_fc2, w, l, tid);
  store_px<4, 1024>(abuf, lac, w, l);          // A2, pitch 1024

  // ---- stage F: Rd[64][256] = A2 @ proto^T (contraction over num_k)
  f32x4 accf[4][2];
  #pragma unroll
  for (int a = 0; a < 4; ++a) { accf[a][0] = zz; accf[a][1] = zz; }
  gemm_px<512, 256, 2, 1024>(accf, abuf, bbuf, w_proto, w, l, tid);
  store_px<2, 512>(abuf, accf, w, l);          // Rd, pitch 512

  // ---- stage G (transposed): yT[512 c][64 m] = o_w[c][f] @ Rd^T
  f32x4 accg[4][4];
  #pragma unroll
  for (int a = 0; a < 4; ++a)
    #pragma unroll
    for (int b = 0; b < 4; ++b) accg[a][b] = zz;
  for (int kk = 0; kk < 4; ++kk) {
    stage_w<256, 512>(bbuf, w_o, kk, tid);
    __syncthreads();
    #pragma unroll
    for (int ks = 0; ks < 2; ++ks) {
      const int kbs = ks * 64 + (l >> 4) * 16;
      bf16x8 of[4];
      #pragma unroll
      for (int j = 0; j < 4; ++j)
        of[j] = ld_a(bbuf, (w + 8 * j) * 16 + (l & 15), 128, kbs);
      #pragma unroll
      for (int ct = 0; ct < 4; ++ct) {
        bf16x8 rdv = ld_a(abuf, ct * 16 + (l & 15), 512, kk * 128 + kbs);
        #pragma unroll
        for (int j = 0; j < 4; ++j)
          accg[j][ct] = __builtin_amdgcn_mfma_f32_16x16x32_bf16(of[j], rdv, accg[j][ct], 0, 0, 0);
      }
    }
    __syncthreads();
  }

  // ---- epilogue: y = gamma*conv + x (coalesced along p), BN partials per channel
  const float gmm = gammap[0];
  #pragma unroll
  for (int j = 0; j < 4; ++j) {
    #pragma unroll
    for (int rr = 0; rr < 4; ++rr) {
      const int c = (w + 8 * j) * 16 + (l >> 4) * 4 + rr;
      const size_t base = ((size_t)(n * 512 + c)) * 4096 + (size_t)p0;
      float sy = 0.f, sq = 0.f;
      #pragma unroll
      for (int ct = 0; ct < 4; ++ct) {
        const int ml = ct * 16 + (l & 15);
        const float y = gmm * accg[j][ct][rr] + x[base + ml];
        out[base + ml] = y;
        sy += y; sq += y * y;
      }
      sy = red16<false>(sy);
      sq = red16<false>(sq);
      if ((l & 15) == 0) {
        psum[(size_t)c * 512 + bid] = sy;
        psq [(size_t)c * 512 + bid] = sq;
      }
    }
  }
}

// ---------------- BN stats: reduce per-block partials -> scale/shift ----------------
__global__ __launch_bounds__(256) void stats_kernel(
    const float* __restrict__ psum, const float* __restrict__ psq,
    const float* __restrict__ bnw,  const float* __restrict__ bnb,
    float* __restrict__ aff)
{
  const int c = blockIdx.x;
  const int t = threadIdx.x;
  float s = psum[(size_t)c * 512 + t] + psum[(size_t)c * 512 + t + 256];
  float q = psq [(size_t)c * 512 + t] + psq [(size_t)c * 512 + t + 256];
  #pragma unroll
  for (int sh = 1; sh < 64; sh <<= 1) {
    s += __shfl_xor(s, sh, 64);
    q += __shfl_xor(q, sh, 64);
  }
  __shared__ float ls[4], lq[4];
  const int wv = t >> 6;
  if ((t & 63) == 0) { ls[wv] = s; lq[wv] = q; }
  __syncthreads();
  if (t == 0) {
    const float S = ls[0] + ls[1] + ls[2] + ls[3];
    const float Q = lq[0] + lq[1] + lq[2] + lq[3];
    const float mean = S * (1.0f / 32768.0f);
    const float var  = Q * (1.0f / 32768.0f) - mean * mean;
    const float inv  = rsqrtf(var + 1e-5f);
    const float sc   = bnw[c] * inv;
    aff[2 * c]     = sc;
    aff[2 * c + 1] = bnb[c] - mean * sc;
  }
}

// ---------------- BN apply (in-place on d_out) ----------------
// out has 16,777,216 floats = 4,194,304 f32x4 vectors (fixed: was 2,097,152
// and left images 4-7 un-normalized -> absmax 0.86)
__global__ __launch_bounds__(256) void norm_kernel(float* __restrict__ out,
                                                   const float* __restrict__ aff)
{
  f32x4* p = (f32x4*)out;
  for (int i = blockIdx.x * blockDim.x + threadIdx.x; i < 4194304;
       i += gridDim.x * blockDim.x) {
    const int c = (i >> 10) & 511;   // 1024 f32x4 vectors per [n][c] plane
    const float sc = aff[2 * c], sh = aff[2 * c + 1];
    f32x4 v = p[i];
    #pragma unroll
    for (int k = 0; k < 4; ++k) v[k] = v[k] * sc + sh;
    p[i] = v;
  }
}

extern "C" void kernel_launch(void* const* d_in, const int* in_sizes, int n_in,
                              void* d_out, int out_size, void* d_ws, size_t ws_size,
                              hipStream_t stream) {
  const float* x     = (const float*)d_in[0];
  const float* theta = (const float*)d_in[1];
  const float* proto = (const float*)d_in[2];
  const float* fc1w  = (const float*)d_in[3];
  const float* fc1b  = (const float*)d_in[4];
  const float* fc2w  = (const float*)d_in[5];
  const float* fc2b  = (const float*)d_in[6];
  const float* ow    = (const float*)d_in[7];
  const float* gamma = (const float*)d_in[8];
  const float* bnw   = (const float*)d_in[9];
  const float* bnb   = (const float*)d_in[10];
  char*  ws   = (char*)d_ws;
  float* out  = (float*)d_out;
  float* psum = (float*)(ws + OFF_PSUM);
  float* psq  = (float*)(ws + OFF_PSQ);
  float* aff  = (float*)(ws + OFF_AFF);

  prep_kernel<<<4096, 256, 0, stream>>>(theta, proto, fc1w, fc2w, ow, ws);

  (void)hipFuncSetAttribute((const void*)mega_kernel,
                            hipFuncAttributeMaxDynamicSharedMemorySize, SMEM_BYTES);
  mega_kernel<<<512, 512, SMEM_BYTES, stream>>>(x, ws, fc1b, fc2b, gamma, out, psum, psq);

  stats_kernel<<<512, 256, 0, stream>>>(psum, psq, bnw, bnb, aff);
  norm_kernel<<<2048, 256, 0, stream>>>(out, aff);
}

// Round 3
// 251.323 us; speedup vs baseline: 1.0032x; 1.0032x over previous
//
#include <hip/hip_runtime.h>

#define DI __device__ __forceinline__

using bf16x8 = __attribute__((ext_vector_type(8))) __bf16;
using bf16x4 = __attribute__((ext_vector_type(4))) __bf16;
using f32x4  = __attribute__((ext_vector_type(4))) float;

typedef unsigned short u16;
typedef unsigned int   u32;

static constexpr float SM_SCALE = 0.0625f;     // 1/sqrt(FEAT=256)
static constexpr float LAMBD    = 1.0f / 512.0f;

// ---------------- workspace byte offsets ----------------
static constexpr size_t OFF_THETA  = 0;         // bf16 [256][512]
static constexpr size_t OFF_PROTOT = 262144;    // bf16 [512][256]  (proto^T)
static constexpr size_t OFF_PROTO  = 524288;    // bf16 [256][512]
static constexpr size_t OFF_FC1    = 786432;    // bf16 [512][512]
static constexpr size_t OFF_FC2    = 1310720;   // bf16 [512][512]
static constexpr size_t OFF_O      = 1835008;   // bf16 [512][256]
static constexpr size_t OFF_PSUM   = 2097152;   // f32 [512 ch][512 blk]
static constexpr size_t OFF_PSQ    = 3145728;   // f32 [512 ch][512 blk]
static constexpr size_t OFF_AFF    = 4194304;   // f32 [512][2] (scale, shift)

// ---------------- LDS layout: 64 KiB total -> 2 blocks/CU ----------------
static constexpr int ABUF = 0;        // 32 KiB: A-operand [64 rows][256 k] bf16, pitch 512B, swizzled
static constexpr int BBUF = 32768;    // 32 KiB: weight slab; softmax scratch aliases here
static constexpr int SMEM_BYTES = 65536;

DI u16 f2b(float f) {
  union { float f; u32 u; } c; c.f = f;
  u32 r = c.u + 0x7FFFu + ((c.u >> 16) & 1u);   // RNE
  return (u16)(r >> 16);
}

// ---------------- prep: weights f32 -> bf16 (+ proto transpose) ----------------
__global__ __launch_bounds__(256) void prep_kernel(
    const float* __restrict__ theta, const float* __restrict__ proto,
    const float* __restrict__ fc1,   const float* __restrict__ fc2,
    const float* __restrict__ ow,    char* __restrict__ ws)
{
  u16* w_theta  = (u16*)(ws + OFF_THETA);
  u16* w_protoT = (u16*)(ws + OFF_PROTOT);
  u16* w_proto  = (u16*)(ws + OFF_PROTO);
  u16* w_fc1    = (u16*)(ws + OFF_FC1);
  u16* w_fc2    = (u16*)(ws + OFF_FC2);
  u16* w_o      = (u16*)(ws + OFF_O);
  for (int i = blockIdx.x * blockDim.x + threadIdx.x; i < 1048576;
       i += gridDim.x * blockDim.x) {
    if (i < 131072) { w_theta[i] = f2b(theta[i]); }
    else if (i < 262144) { int j = i - 131072; int k = j >> 8, f = j & 255;
                           w_protoT[j] = f2b(proto[f * 512 + k]); }
    else if (i < 393216) { int j = i - 262144; w_proto[j] = f2b(proto[j]); }
    else if (i < 655360) { int j = i - 393216; w_fc1[j] = f2b(fc1[j]); }
    else if (i < 917504) { int j = i - 655360; w_fc2[j] = f2b(fc2[j]); }
    else                 { int j = i - 917504; w_o[j]   = f2b(ow[j]); }
  }
}

// ---------------- barriers: raw s_barrier + lgkm drain ONLY (keep vmcnt in flight) ----
DI void bar() {
  asm volatile("s_waitcnt lgkmcnt(0)" ::: "memory");
  __builtin_amdgcn_s_barrier();
}

// ---------------- LDS fragment access ----------------
// ABUF read: [row][k] bf16, pitch 512B, byte-swizzle ^((row&7)<<4)
DI bf16x8 ld_frag(const char* base, int row, int kbyte) {
  return *(const bf16x8*)(base + row * 512 + (kbyte ^ ((row & 7) << 4)));
}

// weight slab: 32 KiB = [NB cols][KSTEP k] bf16.
// KSTEP=32 (NB=512): linear col*64 + kl*16 (wave sweeps contiguous 1KB -> conflict-free)
// KSTEP=64 (NB=256): col*128 + (kl*16 ^ ((col&7)<<4))
template<int WSTRIDE, int KSTEP>
DI void slab_load(bf16x8 (&pf)[4], const __bf16* __restrict__ gsrc, int k0, int tid) {
  constexpr int CPC = KSTEP / 8;   // 16B chunks per col
  #pragma unroll
  for (int q = 0; q < 4; ++q) {
    const int idx = q * 512 + tid;
    const int col = idx / CPC, kl = idx % CPC;
    pf[q] = *(const bf16x8*)(gsrc + (size_t)col * WSTRIDE + k0 + kl * 8);
  }
}
template<int KSTEP>
DI void slab_write(char* bbuf, const bf16x8 (&pf)[4], int tid) {
  #pragma unroll
  for (int q = 0; q < 4; ++q) {
    const int idx = q * 512 + tid;
    int off;
    if constexpr (KSTEP == 32) { const int col = idx >> 2; off = col * 64 + (idx & 3) * 16; }
    else                       { const int col = idx >> 3; off = col * 128 + (((idx & 7) * 16) ^ ((col & 7) << 4)); }
    *(bf16x8*)(bbuf + off) = pf[q];
  }
}
template<int KSTEP>
DI bf16x8 ld_b(const char* bbuf, int col, int ks, int g) {
  if constexpr (KSTEP == 32) return *(const bf16x8*)(bbuf + col * 64 + g * 16);
  else return *(const bf16x8*)(bbuf + col * 128 + (((ks * 64 + g * 16)) ^ ((col & 7) << 4)));
}

// generic GEMM over a 256-wide contraction window resident in ABUF,
// weight slabs prefetched to registers (T14) and staged per phase.
template<int WSTRIDE, int NB, int KSTEP, int CT>
DI void gemm_run(f32x4 (&acc)[4][CT], const char* abuf, char* bbuf,
                 const __bf16* __restrict__ wsrc, int w, int l, int tid) {
  constexpr int NPH = 256 / KSTEP;
  const int g = l >> 4;
  bf16x8 pf[4];
  slab_load<WSTRIDE, KSTEP>(pf, wsrc, 0, tid);
  for (int kk = 0; kk < NPH; ++kk) {
    bar();                                   // prior BBUF readers done / ABUF stores visible
    slab_write<KSTEP>(bbuf, pf, tid);        // data-dep waits vmcnt for pf
    bar();                                   // slab visible
    if (kk + 1 < NPH) slab_load<WSTRIDE, KSTEP>(pf, wsrc, (kk + 1) * KSTEP, tid);
    #pragma unroll
    for (int ks = 0; ks < KSTEP / 32; ++ks) {
      const int akb = kk * KSTEP * 2 + ks * 64 + g * 16;
      bf16x8 af[4];
      #pragma unroll
      for (int r0 = 0; r0 < 4; ++r0) af[r0] = ld_frag(abuf, r0 * 16 + (l & 15), akb);
      #pragma unroll
      for (int j = 0; j < CT; ++j) {
        bf16x8 bf = ld_b<KSTEP>(bbuf, (w + 8 * j) * 16 + (l & 15), ks, g);
        #pragma unroll
        for (int r0 = 0; r0 < 4; ++r0)
          acc[r0][j] = __builtin_amdgcn_mfma_f32_16x16x32_bf16(af[r0], bf, acc[r0][j], 0, 0, 0);
      }
    }
  }
  bar();                                     // all reads done before caller's next LDS writes
}

// ---------------- fragment stores to ABUF (bf16, pitch 512, swizzled) ----------------
template<int CT>
DI void store_f32(char* abuf, const f32x4 (&v)[4][CT], int w, int l) {
  #pragma unroll
  for (int j = 0; j < CT; ++j) {
    const int col = (w + 8 * j) * 16 + (l & 15);
    #pragma unroll
    for (int r0 = 0; r0 < 4; ++r0)
      #pragma unroll
      for (int rr = 0; rr < 4; ++rr) {
        const int row = r0 * 16 + (l >> 4) * 4 + rr;
        *(__bf16*)(abuf + row * 512 + ((col * 2) ^ ((row & 7) << 4))) = (__bf16)v[r0][j][rr];
      }
  }
}
template<int CT>
DI void store_bf16(char* abuf, const bf16x4 (&v)[4][CT], int w, int l) {
  #pragma unroll
  for (int j = 0; j < CT; ++j) {
    const int col = (w + 8 * j) * 16 + (l & 15);
    #pragma unroll
    for (int r0 = 0; r0 < 4; ++r0)
      #pragma unroll
      for (int rr = 0; rr < 4; ++rr) {
        const int row = r0 * 16 + (l >> 4) * 4 + rr;
        *(__bf16*)(abuf + row * 512 + ((col * 2) ^ ((row & 7) << 4))) = v[r0][j][rr];
      }
  }
}

template<bool ISMAX>
DI float red16(float v) {
  #pragma unroll
  for (int s = 1; s < 16; s <<= 1) {
    float o = __shfl_xor(v, s, 64);
    v = ISMAX ? fmaxf(v, o) : (v + o);
  }
  return v;
}

// cross-wave per-row reduction; scratch aliases BBUF (no weight slab live here)
template<bool ISMAX>
DI void row_round(char* smem, int round, float (&part)[4][4], float (&res)[4][4],
                  int w, int l, int tid) {
  float* rrb = (float*)(smem + BBUF + round * 2048);
  float* rfb = (float*)(smem + BBUF + 8192 + round * 256);
  const int g = l >> 4;
  if ((l & 15) == 0) {
    #pragma unroll
    for (int r0 = 0; r0 < 4; ++r0)
      #pragma unroll
      for (int rr = 0; rr < 4; ++rr)
        rrb[(r0 * 16 + g * 4 + rr) * 8 + w] = part[r0][rr];
  }
  __syncthreads();
  if (tid < 64) {
    float m = ISMAX ? -3.0e38f : 0.0f;
    #pragma unroll
    for (int q = 0; q < 8; ++q) {
      float v = rrb[tid * 8 + q];
      m = ISMAX ? fmaxf(m, v) : (m + v);
    }
    rfb[tid] = m;
  }
  __syncthreads();
  #pragma unroll
  for (int r0 = 0; r0 < 4; ++r0)
    #pragma unroll
    for (int rr = 0; rr < 4; ++rr)
      res[r0][rr] = rfb[r0 * 16 + g * 4 + rr];
}

// ---------------- mega: fused chain for 64 pixel-rows per block ----------------
__global__ __launch_bounds__(512, 4) void mega_kernel(
    const float* __restrict__ x, const char* __restrict__ ws,
    const float* __restrict__ fc1b, const float* __restrict__ fc2b,
    const float* __restrict__ gammap, float* __restrict__ out,
    float* __restrict__ psum, float* __restrict__ psq)
{
  extern __shared__ __align__(16) char smem[];
  const int tid = threadIdx.x;
  const int w   = tid >> 6;
  const int l   = tid & 63;
  const int bid = blockIdx.x;
  const int m0  = bid << 6;
  const int n   = m0 >> 12;
  const int p0  = m0 & 4095;

  const __bf16* w_theta  = (const __bf16*)(ws + OFF_THETA);
  const __bf16* w_protoT = (const __bf16*)(ws + OFF_PROTOT);
  const __bf16* w_proto  = (const __bf16*)(ws + OFF_PROTO);
  const __bf16* w_fc1    = (const __bf16*)(ws + OFF_FC1);
  const __bf16* w_fc2    = (const __bf16*)(ws + OFF_FC2);
  const __bf16* w_o      = (const __bf16*)(ws + OFF_O);

  char* abuf = smem + ABUF;
  char* bbuf = smem + BBUF;

  const f32x4 zz = {0.f, 0.f, 0.f, 0.f};

  // ---- stage A: Q[64][256] = X[64][512] @ theta^T, channel halves of 256
  f32x4 accq[4][2];
  #pragma unroll
  for (int a = 0; a < 4; ++a) { accq[a][0] = zz; accq[a][1] = zz; }
  #pragma unroll
  for (int ah = 0; ah < 2; ++ah) {
    #pragma unroll
    for (int q = 0; q < 4; ++q) {
      const int cl = q * 64 + (tid >> 3);           // local channel 0..255
      const int c  = ah * 256 + cl;
      const int j0 = (tid & 7) * 8;
      const float* xp = x + ((size_t)(n * 512 + c)) * 4096 + (size_t)(p0 + j0);
      f32x4 v0 = *(const f32x4*)xp;
      f32x4 v1 = *(const f32x4*)(xp + 4);
      #pragma unroll
      for (int i = 0; i < 8; ++i) {
        const float f = (i < 4) ? v0[i] : v1[i - 4];
        const int row = j0 + i;
        *(__bf16*)(abuf + row * 512 + ((cl * 2) ^ ((row & 7) << 4))) = (__bf16)f;
      }
    }
    gemm_run<512, 256, 64, 2>(accq, abuf, bbuf, w_theta + ah * 256, w, l, tid);
  }

  // ---- stage B: logits[64][512] = Q @ proto
  {
    bf16x4 qb[4][2];
    #pragma unroll
    for (int r0 = 0; r0 < 4; ++r0)
      #pragma unroll
      for (int j = 0; j < 2; ++j)
        #pragma unroll
        for (int rr = 0; rr < 4; ++rr) qb[r0][j][rr] = (__bf16)accq[r0][j][rr];
    store_bf16<2>(abuf, qb, w, l);
  }
  f32x4 lac[4][4];
  #pragma unroll
  for (int a = 0; a < 4; ++a)
    #pragma unroll
    for (int b = 0; b < 4; ++b) lac[a][b] = zz;
  gemm_run<256, 512, 32, 4>(lac, abuf, bbuf, w_protoT, w, l, tid);

  // ---- stage C: softmax -> hard-shrink -> L1 renorm (f32, scratch in BBUF)
  {
    float part[4][4], rres[4][4];
    #pragma unroll
    for (int r0 = 0; r0 < 4; ++r0)
      #pragma unroll
      for (int rr = 0; rr < 4; ++rr) {
        float m2 = lac[r0][0][rr];
        #pragma unroll
        for (int j = 1; j < 4; ++j) m2 = fmaxf(m2, lac[r0][j][rr]);
        part[r0][rr] = red16<true>(m2);
      }
    row_round<true>(smem, 0, part, rres, w, l, tid);
    #pragma unroll
    for (int r0 = 0; r0 < 4; ++r0)
      #pragma unroll
      for (int rr = 0; rr < 4; ++rr) {
        const float mr = rres[r0][rr];
        float s2 = 0.f;
        #pragma unroll
        for (int j = 0; j < 4; ++j) {
          float e = __expf((lac[r0][j][rr] - mr) * SM_SCALE);
          lac[r0][j][rr] = e;
          s2 += e;
        }
        part[r0][rr] = red16<false>(s2);
      }
    row_round<false>(smem, 1, part, rres, w, l, tid);
    #pragma unroll
    for (int r0 = 0; r0 < 4; ++r0)
      #pragma unroll
      for (int rr = 0; rr < 4; ++rr) {
        const float rinv = 1.0f / rres[r0][rr];
        float s2 = 0.f;
        #pragma unroll
        for (int j = 0; j < 4; ++j) {
          float s = lac[r0][j][rr] * rinv;
          float t = s - LAMBD;
          float a = __fdividef(fmaxf(t, 0.f) * s, fabsf(t) + 1e-12f);
          lac[r0][j][rr] = a;
          s2 += a;
        }
        part[r0][rr] = red16<false>(s2);
      }
    row_round<false>(smem, 2, part, rres, w, l, tid);
    #pragma unroll
    for (int r0 = 0; r0 < 4; ++r0)
      #pragma unroll
      for (int rr = 0; rr < 4; ++rr) {
        const float rinv = 1.0f / (rres[r0][rr] + 1e-12f);
        #pragma unroll
        for (int j = 0; j < 4; ++j) lac[r0][j][rr] *= rinv;
      }
  }

  // attn A1 as bf16 regs (residual base; also the A-operand source for fc1)
  bf16x4 pa[4][4];
  #pragma unroll
  for (int r0 = 0; r0 < 4; ++r0)
    #pragma unroll
    for (int j = 0; j < 4; ++j)
      #pragma unroll
      for (int rr = 0; rr < 4; ++rr) pa[r0][j][rr] = (__bf16)lac[r0][j][rr];
  // lac dead from here

  // ---- stage D: R = relu(A1 @ fc1^T + b1), in two 256-col halves rh
  bf16x4 prb0[4][2];                    // R half 0 kept in regs; R half 1 goes to ABUF
  #pragma unroll
  for (int rh = 0; rh < 2; ++rh) {
    f32x4 accd[4][2];
    #pragma unroll
    for (int a = 0; a < 4; ++a) { accd[a][0] = zz; accd[a][1] = zz; }
    #pragma unroll
    for (int ah = 0; ah < 2; ++ah) {
      bf16x4 t[4][2];
      #pragma unroll
      for (int r0 = 0; r0 < 4; ++r0)
        #pragma unroll
        for (int jj = 0; jj < 2; ++jj) t[r0][jj] = pa[r0][2 * ah + jj];
      store_bf16<2>(abuf, t, w, l);
      gemm_run<512, 256, 64, 2>(accd, abuf, bbuf,
                                w_fc1 + (size_t)rh * 256 * 512 + ah * 256, w, l, tid);
    }
    #pragma unroll
    for (int j = 0; j < 2; ++j) {
      const float b1 = fc1b[rh * 256 + (w + 8 * j) * 16 + (l & 15)];
      #pragma unroll
      for (int r0 = 0; r0 < 4; ++r0)
        #pragma unroll
        for (int rr = 0; rr < 4; ++rr)
          accd[r0][j][rr] = fmaxf(accd[r0][j][rr] + b1, 0.f);
    }
    if (rh == 0) {
      #pragma unroll
      for (int r0 = 0; r0 < 4; ++r0)
        #pragma unroll
        for (int j = 0; j < 2; ++j)
          #pragma unroll
          for (int rr = 0; rr < 4; ++rr) prb0[r0][j][rr] = (__bf16)accd[r0][j][rr];
    } else {
      store_f32<2>(abuf, accd, w, l);   // R1 -> ABUF (consumed first by stage E)
    }
  }

  // ---- stage E: A2 = A1 + R @ fc2^T + b2 (acc init from pa + b2; contract R1 then R0)
  f32x4 acce[4][4];
  #pragma unroll
  for (int j = 0; j < 4; ++j) {
    const float b2 = fc2b[(w + 8 * j) * 16 + (l & 15)];
    #pragma unroll
    for (int r0 = 0; r0 < 4; ++r0)
      #pragma unroll
      for (int rr = 0; rr < 4; ++rr)
        acce[r0][j][rr] = (float)pa[r0][j][rr] + b2;
  }
  gemm_run<512, 512, 32, 4>(acce, abuf, bbuf, w_fc2 + 256, w, l, tid);  // R1 (hidden 256..511)
  store_bf16<2>(abuf, prb0, w, l);
  gemm_run<512, 512, 32, 4>(acce, abuf, bbuf, w_fc2, w, l, tid);        // R0 (hidden 0..255)

  // ---- stage F: Rd[64][256] = A2 @ proto^T, num_k halves
  bf16x4 pab[4][4];
  #pragma unroll
  for (int r0 = 0; r0 < 4; ++r0)
    #pragma unroll
    for (int j = 0; j < 4; ++j)
      #pragma unroll
      for (int rr = 0; rr < 4; ++rr) pab[r0][j][rr] = (__bf16)acce[r0][j][rr];
  f32x4 accf[4][2];
  #pragma unroll
  for (int a = 0; a < 4; ++a) { accf[a][0] = zz; accf[a][1] = zz; }
  #pragma unroll
  for (int ah = 0; ah < 2; ++ah) {
    bf16x4 t[4][2];
    #pragma unroll
    for (int r0 = 0; r0 < 4; ++r0)
      #pragma unroll
      for (int jj = 0; jj < 2; ++jj) t[r0][jj] = pab[r0][2 * ah + jj];
    store_bf16<2>(abuf, t, w, l);
    gemm_run<512, 256, 64, 2>(accf, abuf, bbuf, w_proto + ah * 256, w, l, tid);
  }

  // ---- stage G (swapped operands): yT[512 c][64 m] = o_w @ Rd^T
  {
    bf16x4 prd[4][2];
    #pragma unroll
    for (int r0 = 0; r0 < 4; ++r0)
      #pragma unroll
      for (int j = 0; j < 2; ++j)
        #pragma unroll
        for (int rr = 0; rr < 4; ++rr) prd[r0][j][rr] = (__bf16)accf[r0][j][rr];
    store_bf16<2>(abuf, prd, w, l);
  }
  f32x4 accg[4][4];
  #pragma unroll
  for (int a = 0; a < 4; ++a)
    #pragma unroll
    for (int b = 0; b < 4; ++b) accg[a][b] = zz;
  {
    const int g = l >> 4;
    bf16x8 pf[4];
    slab_load<256, 32>(pf, w_o, 0, tid);
    for (int kk = 0; kk < 8; ++kk) {
      bar();
      slab_write<32>(bbuf, pf, tid);
      bar();
      if (kk + 1 < 8) slab_load<256, 32>(pf, w_o, (kk + 1) * 32, tid);
      const int akb = kk * 64 + g * 16;
      bf16x8 of[4];
      #pragma unroll
      for (int j = 0; j < 4; ++j)
        of[j] = ld_b<32>(bbuf, (w + 8 * j) * 16 + (l & 15), 0, g);
      #pragma unroll
      for (int ct = 0; ct < 4; ++ct) {
        bf16x8 rdv = ld_frag(abuf, ct * 16 + (l & 15), akb);
        #pragma unroll
        for (int j = 0; j < 4; ++j)
          accg[j][ct] = __builtin_amdgcn_mfma_f32_16x16x32_bf16(of[j], rdv, accg[j][ct], 0, 0, 0);
      }
    }
  }

  // ---- epilogue: y = gamma*conv + x, per-channel BN partials
  const float gmm = gammap[0];
  #pragma unroll
  for (int j = 0; j < 4; ++j) {
    #pragma unroll
    for (int rr = 0; rr < 4; ++rr) {
      const int c = (w + 8 * j) * 16 + (l >> 4) * 4 + rr;
      const size_t base = ((size_t)(n * 512 + c)) * 4096 + (size_t)p0;
      float sy = 0.f, sq = 0.f;
      #pragma unroll
      for (int ct = 0; ct < 4; ++ct) {
        const int ml = ct * 16 + (l & 15);
        const float y = gmm * accg[j][ct][rr] + x[base + ml];
        out[base + ml] = y;
        sy += y; sq += y * y;
      }
      sy = red16<false>(sy);
      sq = red16<false>(sq);
      if ((l & 15) == 0) {
        psum[(size_t)c * 512 + bid] = sy;
        psq [(size_t)c * 512 + bid] = sq;
      }
    }
  }
}

// ---------------- BN stats ----------------
__global__ __launch_bounds__(256) void stats_kernel(
    const float* __restrict__ psum, const float* __restrict__ psq,
    const float* __restrict__ bnw,  const float* __restrict__ bnb,
    float* __restrict__ aff)
{
  const int c = blockIdx.x;
  const int t = threadIdx.x;
  float s = psum[(size_t)c * 512 + t] + psum[(size_t)c * 512 + t + 256];
  float q = psq [(size_t)c * 512 + t] + psq [(size_t)c * 512 + t + 256];
  #pragma unroll
  for (int sh = 1; sh < 64; sh <<= 1) {
    s += __shfl_xor(s, sh, 64);
    q += __shfl_xor(q, sh, 64);
  }
  __shared__ float ls[4], lq[4];
  const int wv = t >> 6;
  if ((t & 63) == 0) { ls[wv] = s; lq[wv] = q; }
  __syncthreads();
  if (t == 0) {
    const float S = ls[0] + ls[1] + ls[2] + ls[3];
    const float Q = lq[0] + lq[1] + lq[2] + lq[3];
    const float mean = S * (1.0f / 32768.0f);
    const float var  = Q * (1.0f / 32768.0f) - mean * mean;
    const float inv  = rsqrtf(var + 1e-5f);
    const float sc   = bnw[c] * inv;
    aff[2 * c]     = sc;
    aff[2 * c + 1] = bnb[c] - mean * sc;
  }
}

// ---------------- BN apply (full tensor: 4,194,304 f32x4) ----------------
__global__ __launch_bounds__(256) void norm_kernel(float* __restrict__ out,
                                                   const float* __restrict__ aff)
{
  f32x4* p = (f32x4*)out;
  for (int i = blockIdx.x * blockDim.x + threadIdx.x; i < 4194304;
       i += gridDim.x * blockDim.x) {
    const int c = (i >> 10) & 511;
    const float sc = aff[2 * c], sh = aff[2 * c + 1];
    f32x4 v = p[i];
    #pragma unroll
    for (int k = 0; k < 4; ++k) v[k] = v[k] * sc + sh;
    p[i] = v;
  }
}

extern "C" void kernel_launch(void* const* d_in, const int* in_sizes, int n_in,
                              void* d_out, int out_size, void* d_ws, size_t ws_size,
                              hipStream_t stream) {
  const float* x     = (const float*)d_in[0];
  const float* theta = (const float*)d_in[1];
  const float* proto = (const float*)d_in[2];
  const float* fc1w  = (const float*)d_in[3];
  const float* fc1b  = (const float*)d_in[4];
  const float* fc2w  = (const float*)d_in[5];
  const float* fc2b  = (const float*)d_in[6];
  const float* ow    = (const float*)d_in[7];
  const float* gamma = (const float*)d_in[8];
  const float* bnw   = (const float*)d_in[9];
  const float* bnb   = (const float*)d_in[10];
  char*  ws   = (char*)d_ws;
  float* out  = (float*)d_out;
  float* psum = (float*)(ws + OFF_PSUM);
  float* psq  = (float*)(ws + OFF_PSQ);
  float* aff  = (float*)(ws + OFF_AFF);

  prep_kernel<<<4096, 256, 0, stream>>>(theta, proto, fc1w, fc2w, ow, ws);

  (void)hipFuncSetAttribute((const void*)mega_kernel,
                            hipFuncAttributeMaxDynamicSharedMemorySize, SMEM_BYTES);
  mega_kernel<<<512, 512, SMEM_BYTES, stream>>>(x, ws, fc1b, fc2b, gamma, out, psum, psq);

  stats_kernel<<<512, 256, 0, stream>>>(psum, psq, bnw, bnb, aff);
  norm_kernel<<<2048, 256, 0, stream>>>(out, aff);
}

// Round 4
// 248.006 us; speedup vs baseline: 1.0166x; 1.0134x over previous
//
#include <hip/hip_runtime.h>

#define DI __device__ __forceinline__

using bf16x8 = __attribute__((ext_vector_type(8))) __bf16;
using bf16x4 = __attribute__((ext_vector_type(4))) __bf16;
using f32x4  = __attribute__((ext_vector_type(4))) float;

typedef unsigned short u16;
typedef unsigned int   u32;

static constexpr float SM_SCALE = 0.0625f;     // 1/sqrt(FEAT=256)
static constexpr float LAMBD    = 1.0f / 512.0f;

// ---------------- workspace byte offsets ----------------
static constexpr size_t OFF_THETA  = 0;         // bf16 [256][512]
static constexpr size_t OFF_PROTOT = 262144;    // bf16 [512][256]  (proto^T)
static constexpr size_t OFF_PROTO  = 524288;    // bf16 [256][512]
static constexpr size_t OFF_FC1    = 786432;    // bf16 [512][512]
static constexpr size_t OFF_FC2    = 1310720;   // bf16 [512][512]
static constexpr size_t OFF_O      = 1835008;   // bf16 [512][256]
static constexpr size_t OFF_PSUM   = 2097152;   // f32 [512 ch][512 blk]
static constexpr size_t OFF_PSQ    = 3145728;   // f32 [512 ch][512 blk]
static constexpr size_t OFF_AFF    = 4194304;   // f32 [512][2] (scale, shift)

// ---------------- LDS: two 32 KiB A-windows + small reduce scratch ----------------
static constexpr int AB0 = 0;        // [64 rows][256 k] bf16, pitch 512B, swizzled
static constexpr int AB1 = 32768;    // second window (R0 home in stages D/E)
static constexpr int SCR = 65536;    // 3x2048 rrb + 3x256 rfb
static constexpr int SMEM_BYTES = 72448;

DI u16 f2b(float f) {
  union { float f; u32 u; } c; c.f = f;
  u32 r = c.u + 0x7FFFu + ((c.u >> 16) & 1u);   // RNE
  return (u16)(r >> 16);
}

// ---------------- prep: weights f32 -> bf16 (+ proto transpose) ----------------
__global__ __launch_bounds__(256) void prep_kernel(
    const float* __restrict__ theta, const float* __restrict__ proto,
    const float* __restrict__ fc1,   const float* __restrict__ fc2,
    const float* __restrict__ ow,    char* __restrict__ ws)
{
  u16* w_theta  = (u16*)(ws + OFF_THETA);
  u16* w_protoT = (u16*)(ws + OFF_PROTOT);
  u16* w_proto  = (u16*)(ws + OFF_PROTO);
  u16* w_fc1    = (u16*)(ws + OFF_FC1);
  u16* w_fc2    = (u16*)(ws + OFF_FC2);
  u16* w_o      = (u16*)(ws + OFF_O);
  for (int i = blockIdx.x * blockDim.x + threadIdx.x; i < 1048576;
       i += gridDim.x * blockDim.x) {
    if (i < 131072) { w_theta[i] = f2b(theta[i]); }
    else if (i < 262144) { int j = i - 131072; int k = j >> 8, f = j & 255;
                           w_protoT[j] = f2b(proto[f * 512 + k]); }
    else if (i < 393216) { int j = i - 262144; w_proto[j] = f2b(proto[j]); }
    else if (i < 655360) { int j = i - 393216; w_fc1[j] = f2b(fc1[j]); }
    else if (i < 917504) { int j = i - 655360; w_fc2[j] = f2b(fc2[j]); }
    else                 { int j = i - 917504; w_o[j]   = f2b(ow[j]); }
  }
}

// ---------------- barrier: lgkm drain only (global loads stay in flight) ----------
DI void bar() {
  asm volatile("s_waitcnt lgkmcnt(0)" ::: "memory");
  __builtin_amdgcn_s_barrier();
}

// ---------------- LDS fragment access: [row][k] bf16, pitch 512B, swizzled ----------
DI bf16x8 ld_frag(const char* base, int row, int kbyte) {
  return *(const bf16x8*)(base + row * 512 + (kbyte ^ ((row & 7) << 4)));
}

// ---------------- K=256-window GEMM, B-fragments DIRECT from global (L2) ----------
// acc[4 rowtiles][CT coltiles] += A_win[64][256] @ W[cols][K] (W row-major [col][k])
template<int W, int CT>
DI void gemm_win(f32x4 (&acc)[4][CT], const char* awin,
                 const __bf16* __restrict__ wbase, int kw0, int w, int l) {
  const int g  = l >> 4;
  const int lr = l & 15;
  const __bf16* wp[CT];
  #pragma unroll
  for (int j = 0; j < CT; ++j)
    wp[j] = wbase + (size_t)(((w + 8 * j) << 4) + lr) * W + kw0 + g * 8;
  #pragma unroll
  for (int kk = 0; kk < 8; ++kk) {
    bf16x8 af[4];
    #pragma unroll
    for (int r0 = 0; r0 < 4; ++r0)
      af[r0] = ld_frag(awin, r0 * 16 + lr, kk * 64 + g * 16);
    #pragma unroll
    for (int j = 0; j < CT; ++j) {
      bf16x8 bf = *(const bf16x8*)(wp[j] + kk * 32);
      #pragma unroll
      for (int r0 = 0; r0 < 4; ++r0)
        acc[r0][j] = __builtin_amdgcn_mfma_f32_16x16x32_bf16(af[r0], bf, acc[r0][j], 0, 0, 0);
    }
  }
}

// ---------------- fragment stores to an A-window (bf16, pitch 512, swizzled) -------
template<int CT>
DI void store_f32(char* aw, const f32x4 (&v)[4][CT], int w, int l) {
  #pragma unroll
  for (int j = 0; j < CT; ++j) {
    const int col = (w + 8 * j) * 16 + (l & 15);
    #pragma unroll
    for (int r0 = 0; r0 < 4; ++r0)
      #pragma unroll
      for (int rr = 0; rr < 4; ++rr) {
        const int row = r0 * 16 + (l >> 4) * 4 + rr;
        *(__bf16*)(aw + row * 512 + ((col * 2) ^ ((row & 7) << 4))) = (__bf16)v[r0][j][rr];
      }
  }
}
template<int CT>
DI void store_bf16(char* aw, const bf16x4 (&v)[4][CT], int w, int l) {
  #pragma unroll
  for (int j = 0; j < CT; ++j) {
    const int col = (w + 8 * j) * 16 + (l & 15);
    #pragma unroll
    for (int r0 = 0; r0 < 4; ++r0)
      #pragma unroll
      for (int rr = 0; rr < 4; ++rr) {
        const int row = r0 * 16 + (l >> 4) * 4 + rr;
        *(__bf16*)(aw + row * 512 + ((col * 2) ^ ((row & 7) << 4))) = v[r0][j][rr];
      }
  }
}

template<bool ISMAX>
DI float red16(float v) {
  #pragma unroll
  for (int s = 1; s < 16; s <<= 1) {
    float o = __shfl_xor(v, s, 64);
    v = ISMAX ? fmaxf(v, o) : (v + o);
  }
  return v;
}

// cross-wave per-row reduction through SCR
template<bool ISMAX>
DI void row_round(char* smem, int round, float (&part)[4][4], float (&res)[4][4],
                  int w, int l, int tid) {
  float* rrb = (float*)(smem + SCR + round * 2048);
  float* rfb = (float*)(smem + SCR + 6144 + round * 256);
  const int g = l >> 4;
  if ((l & 15) == 0) {
    #pragma unroll
    for (int r0 = 0; r0 < 4; ++r0)
      #pragma unroll
      for (int rr = 0; rr < 4; ++rr)
        rrb[(r0 * 16 + g * 4 + rr) * 8 + w] = part[r0][rr];
  }
  bar();
  if (tid < 64) {
    float m = ISMAX ? -3.0e38f : 0.0f;
    #pragma unroll
    for (int q = 0; q < 8; ++q) {
      float v = rrb[tid * 8 + q];
      m = ISMAX ? fmaxf(m, v) : (m + v);
    }
    rfb[tid] = m;
  }
  bar();
  #pragma unroll
  for (int r0 = 0; r0 < 4; ++r0)
    #pragma unroll
    for (int rr = 0; rr < 4; ++rr)
      res[r0][rr] = rfb[r0 * 16 + g * 4 + rr];
}

// ---------------- mega: fused chain for 64 pixel-rows per block ----------------
__global__ __launch_bounds__(512, 4) void mega_kernel(
    const float* __restrict__ x, const char* __restrict__ ws,
    const float* __restrict__ fc1b, const float* __restrict__ fc2b,
    const float* __restrict__ gammap, float* __restrict__ out,
    float* __restrict__ psum, float* __restrict__ psq)
{
  extern __shared__ __align__(16) char smem[];
  const int tid = threadIdx.x;
  const int w   = tid >> 6;
  const int l   = tid & 63;
  const int bid = blockIdx.x;
  const int m0  = bid << 6;
  const int n   = m0 >> 12;
  const int p0  = m0 & 4095;

  const __bf16* w_theta  = (const __bf16*)(ws + OFF_THETA);
  const __bf16* w_protoT = (const __bf16*)(ws + OFF_PROTOT);
  const __bf16* w_proto  = (const __bf16*)(ws + OFF_PROTO);
  const __bf16* w_fc1    = (const __bf16*)(ws + OFF_FC1);
  const __bf16* w_fc2    = (const __bf16*)(ws + OFF_FC2);
  const __bf16* w_o      = (const __bf16*)(ws + OFF_O);

  char* ab0 = smem + AB0;
  char* ab1 = smem + AB1;

  const f32x4 zz = {0.f, 0.f, 0.f, 0.f};

  // ---- stage A: Q[64][256] = X[64][512] @ theta^T (channel windows of 256)
  f32x4 accq[4][2];
  #pragma unroll
  for (int a = 0; a < 4; ++a) { accq[a][0] = zz; accq[a][1] = zz; }
  #pragma unroll
  for (int ah = 0; ah < 2; ++ah) {
    bar();                                    // prior window readers done
    #pragma unroll
    for (int q = 0; q < 4; ++q) {
      const int cl = q * 64 + (tid >> 3);
      const int c  = ah * 256 + cl;
      const int j0 = (tid & 7) * 8;
      const float* xp = x + ((size_t)(n * 512 + c)) * 4096 + (size_t)(p0 + j0);
      f32x4 v0 = *(const f32x4*)xp;
      f32x4 v1 = *(const f32x4*)(xp + 4);
      #pragma unroll
      for (int i = 0; i < 8; ++i) {
        const float f = (i < 4) ? v0[i] : v1[i - 4];
        const int row = j0 + i;
        *(__bf16*)(ab0 + row * 512 + ((cl * 2) ^ ((row & 7) << 4))) = (__bf16)f;
      }
    }
    bar();                                    // window visible
    gemm_win<512, 2>(accq, ab0, w_theta, ah * 256, w, l);
  }

  // ---- stage B: logits[64][512] = Q @ proto (protoT operand, K=256)
  {
    bf16x4 qb[4][2];
    #pragma unroll
    for (int r0 = 0; r0 < 4; ++r0)
      #pragma unroll
      for (int j = 0; j < 2; ++j)
        #pragma unroll
        for (int rr = 0; rr < 4; ++rr) qb[r0][j][rr] = (__bf16)accq[r0][j][rr];
    bar();
    store_bf16<2>(ab0, qb, w, l);
    bar();
  }
  f32x4 lac[4][4];
  #pragma unroll
  for (int a = 0; a < 4; ++a)
    #pragma unroll
    for (int b = 0; b < 4; ++b) lac[a][b] = zz;
  gemm_win<256, 4>(lac, ab0, w_protoT, 0, w, l);

  // ---- stage C: softmax -> hard-shrink -> L1 renorm (f32)
  {
    float part[4][4], rres[4][4];
    #pragma unroll
    for (int r0 = 0; r0 < 4; ++r0)
      #pragma unroll
      for (int rr = 0; rr < 4; ++rr) {
        float m2 = lac[r0][0][rr];
        #pragma unroll
        for (int j = 1; j < 4; ++j) m2 = fmaxf(m2, lac[r0][j][rr]);
        part[r0][rr] = red16<true>(m2);
      }
    row_round<true>(smem, 0, part, rres, w, l, tid);
    #pragma unroll
    for (int r0 = 0; r0 < 4; ++r0)
      #pragma unroll
      for (int rr = 0; rr < 4; ++rr) {
        const float mr = rres[r0][rr];
        float s2 = 0.f;
        #pragma unroll
        for (int j = 0; j < 4; ++j) {
          float e = __expf((lac[r0][j][rr] - mr) * SM_SCALE);
          lac[r0][j][rr] = e;
          s2 += e;
        }
        part[r0][rr] = red16<false>(s2);
      }
    row_round<false>(smem, 1, part, rres, w, l, tid);
    #pragma unroll
    for (int r0 = 0; r0 < 4; ++r0)
      #pragma unroll
      for (int rr = 0; rr < 4; ++rr) {
        const float rinv = 1.0f / rres[r0][rr];
        float s2 = 0.f;
        #pragma unroll
        for (int j = 0; j < 4; ++j) {
          float s = lac[r0][j][rr] * rinv;
          float t = s - LAMBD;
          float a = __fdividef(fmaxf(t, 0.f) * s, fabsf(t) + 1e-12f);
          lac[r0][j][rr] = a;
          s2 += a;
        }
        part[r0][rr] = red16<false>(s2);
      }
    row_round<false>(smem, 2, part, rres, w, l, tid);
    #pragma unroll
    for (int r0 = 0; r0 < 4; ++r0)
      #pragma unroll
      for (int rr = 0; rr < 4; ++rr) {
        const float rinv = 1.0f / (rres[r0][rr] + 1e-12f);
        #pragma unroll
        for (int j = 0; j < 4; ++j) lac[r0][j][rr] *= rinv;
      }
  }

  // A1 (attn) as packed bf16 regs: residual base + fc1 A-operand source
  bf16x4 pa[4][4];
  #pragma unroll
  for (int r0 = 0; r0 < 4; ++r0)
    #pragma unroll
    for (int j = 0; j < 4; ++j)
      #pragma unroll
      for (int rr = 0; rr < 4; ++rr) pa[r0][j][rr] = (__bf16)lac[r0][j][rr];

  // ---- stage D: R = relu(A1 @ fc1^T + b1); R0 -> AB1 (LDS), R1 -> prb regs
  bf16x4 prb[4][2];
  #pragma unroll
  for (int rh = 0; rh < 2; ++rh) {
    f32x4 accd[4][2];
    #pragma unroll
    for (int a = 0; a < 4; ++a) { accd[a][0] = zz; accd[a][1] = zz; }
    #pragma unroll
    for (int ah = 0; ah < 2; ++ah) {
      bf16x4 t[4][2];
      #pragma unroll
      for (int r0 = 0; r0 < 4; ++r0)
        #pragma unroll
        for (int jj = 0; jj < 2; ++jj) t[r0][jj] = pa[r0][2 * ah + jj];
      bar();
      store_bf16<2>(ab0, t, w, l);
      bar();
      gemm_win<512, 2>(accd, ab0, w_fc1 + (size_t)rh * 131072, ah * 256, w, l);
    }
    #pragma unroll
    for (int j = 0; j < 2; ++j) {
      const float b1 = fc1b[rh * 256 + (w + 8 * j) * 16 + (l & 15)];
      #pragma unroll
      for (int r0 = 0; r0 < 4; ++r0)
        #pragma unroll
        for (int rr = 0; rr < 4; ++rr)
          accd[r0][j][rr] = fmaxf(accd[r0][j][rr] + b1, 0.f);
    }
    if (rh == 0) {
      store_f32<2>(ab1, accd, w, l);          // R0 home: AB1 (read in stage E)
    } else {
      #pragma unroll
      for (int r0 = 0; r0 < 4; ++r0)
        #pragma unroll
        for (int j = 0; j < 2; ++j)
          #pragma unroll
          for (int rr = 0; rr < 4; ++rr) prb[r0][j][rr] = (__bf16)accd[r0][j][rr];
    }
  }

  // stage R1 -> AB0 once; then E runs with both R halves resident
  bar();
  store_bf16<2>(ab0, prb, w, l);
  bar();

  // ---- stage E: A2 = A1 + R @ fc2^T + b2, col-halved (acce = 32 regs)
  bf16x4 pab[4][4];
  #pragma unroll
  for (int ch = 0; ch < 2; ++ch) {
    f32x4 acce[4][2];
    #pragma unroll
    for (int jj = 0; jj < 2; ++jj) {
      const float b2 = fc2b[ch * 256 + (w + 8 * jj) * 16 + (l & 15)];
      #pragma unroll
      for (int r0 = 0; r0 < 4; ++r0)
        #pragma unroll
        for (int rr = 0; rr < 4; ++rr)
          acce[r0][jj][rr] = (float)pa[r0][2 * ch + jj][rr] + b2;
    }
    gemm_win<512, 2>(acce, ab1, w_fc2 + (size_t)ch * 131072, 0,   w, l);  // R0, k 0..255
    gemm_win<512, 2>(acce, ab0, w_fc2 + (size_t)ch * 131072, 256, w, l);  // R1, k 256..511
    #pragma unroll
    for (int r0 = 0; r0 < 4; ++r0)
      #pragma unroll
      for (int jj = 0; jj < 2; ++jj)
        #pragma unroll
        for (int rr = 0; rr < 4; ++rr) pab[r0][2 * ch + jj][rr] = (__bf16)acce[r0][jj][rr];
  }

  // ---- stage F: Rd[64][256] = A2 @ proto^T (K = num_k = 512, windows of 256)
  f32x4 accf[4][2];
  #pragma unroll
  for (int a = 0; a < 4; ++a) { accf[a][0] = zz; accf[a][1] = zz; }
  #pragma unroll
  for (int ah = 0; ah < 2; ++ah) {
    bf16x4 t[4][2];
    #pragma unroll
    for (int r0 = 0; r0 < 4; ++r0)
      #pragma unroll
      for (int jj = 0; jj < 2; ++jj) t[r0][jj] = pab[r0][2 * ah + jj];
    bar();
    store_bf16<2>(ab0, t, w, l);
    bar();
    gemm_win<512, 2>(accf, ab0, w_proto, ah * 256, w, l);
  }

  // ---- stage G (swapped operands): yT[512 c][64 m] = o_w @ Rd^T
  {
    bf16x4 prd[4][2];
    #pragma unroll
    for (int r0 = 0; r0 < 4; ++r0)
      #pragma unroll
      for (int j = 0; j < 2; ++j)
        #pragma unroll
        for (int rr = 0; rr < 4; ++rr) prd[r0][j][rr] = (__bf16)accf[r0][j][rr];
    bar();
    store_bf16<2>(ab0, prd, w, l);
    bar();
  }
  f32x4 accg[4][4];
  #pragma unroll
  for (int a = 0; a < 4; ++a)
    #pragma unroll
    for (int b = 0; b < 4; ++b) accg[a][b] = zz;
  {
    const int g  = l >> 4;
    const int lr = l & 15;
    const __bf16* wp[4];
    #pragma unroll
    for (int j = 0; j < 4; ++j)
      wp[j] = w_o + (size_t)(((w + 8 * j) << 4) + lr) * 256 + g * 8;
    #pragma unroll
    for (int kk = 0; kk < 8; ++kk) {
      bf16x8 of[4];
      #pragma unroll
      for (int j = 0; j < 4; ++j) of[j] = *(const bf16x8*)(wp[j] + kk * 32);
      #pragma unroll
      for (int ct = 0; ct < 4; ++ct) {
        bf16x8 rdv = ld_frag(ab0, ct * 16 + lr, kk * 64 + g * 16);
        #pragma unroll
        for (int j = 0; j < 4; ++j)
          accg[j][ct] = __builtin_amdgcn_mfma_f32_16x16x32_bf16(of[j], rdv, accg[j][ct], 0, 0, 0);
      }
    }
  }

  // ---- epilogue: y = gamma*conv + x (coalesced along p), BN partials per channel
  const float gmm = gammap[0];
  #pragma unroll
  for (int j = 0; j < 4; ++j) {
    #pragma unroll
    for (int rr = 0; rr < 4; ++rr) {
      const int c = (w + 8 * j) * 16 + (l >> 4) * 4 + rr;
      const size_t base = ((size_t)(n * 512 + c)) * 4096 + (size_t)p0;
      float sy = 0.f, sq = 0.f;
      #pragma unroll
      for (int ct = 0; ct < 4; ++ct) {
        const int ml = ct * 16 + (l & 15);
        const float y = gmm * accg[j][ct][rr] + x[base + ml];
        out[base + ml] = y;
        sy += y; sq += y * y;
      }
      sy = red16<false>(sy);
      sq = red16<false>(sq);
      if ((l & 15) == 0) {
        psum[(size_t)c * 512 + bid] = sy;
        psq [(size_t)c * 512 + bid] = sq;
      }
    }
  }
}

// ---------------- BN stats ----------------
__global__ __launch_bounds__(256) void stats_kernel(
    const float* __restrict__ psum, const float* __restrict__ psq,
    const float* __restrict__ bnw,  const float* __restrict__ bnb,
    float* __restrict__ aff)
{
  const int c = blockIdx.x;
  const int t = threadIdx.x;
  float s = psum[(size_t)c * 512 + t] + psum[(size_t)c * 512 + t + 256];
  float q = psq [(size_t)c * 512 + t] + psq [(size_t)c * 512 + t + 256];
  #pragma unroll
  for (int sh = 1; sh < 64; sh <<= 1) {
    s += __shfl_xor(s, sh, 64);
    q += __shfl_xor(q, sh, 64);
  }
  __shared__ float ls[4], lq[4];
  const int wv = t >> 6;
  if ((t & 63) == 0) { ls[wv] = s; lq[wv] = q; }
  __syncthreads();
  if (t == 0) {
    const float S = ls[0] + ls[1] + ls[2] + ls[3];
    const float Q = lq[0] + lq[1] + lq[2] + lq[3];
    const float mean = S * (1.0f / 32768.0f);
    const float var  = Q * (1.0f / 32768.0f) - mean * mean;
    const float inv  = rsqrtf(var + 1e-5f);
    const float sc   = bnw[c] * inv;
    aff[2 * c]     = sc;
    aff[2 * c + 1] = bnb[c] - mean * sc;
  }
}

// ---------------- BN apply (full tensor: 4,194,304 f32x4) ----------------
__global__ __launch_bounds__(256) void norm_kernel(float* __restrict__ out,
                                                   const float* __restrict__ aff)
{
  f32x4* p = (f32x4*)out;
  for (int i = blockIdx.x * blockDim.x + threadIdx.x; i < 4194304;
       i += gridDim.x * blockDim.x) {
    const int c = (i >> 10) & 511;
    const float sc = aff[2 * c], sh = aff[2 * c + 1];
    f32x4 v = p[i];
    #pragma unroll
    for (int k = 0; k < 4; ++k) v[k] = v[k] * sc + sh;
    p[i] = v;
  }
}

extern "C" void kernel_launch(void* const* d_in, const int* in_sizes, int n_in,
                              void* d_out, int out_size, void* d_ws, size_t ws_size,
                              hipStream_t stream) {
  const float* x     = (const float*)d_in[0];
  const float* theta = (const float*)d_in[1];
  const float* proto = (const float*)d_in[2];
  const float* fc1w  = (const float*)d_in[3];
  const float* fc1b  = (const float*)d_in[4];
  const float* fc2w  = (const float*)d_in[5];
  const float* fc2b  = (const float*)d_in[6];
  const float* ow    = (const float*)d_in[7];
  const float* gamma = (const float*)d_in[8];
  const float* bnw   = (const float*)d_in[9];
  const float* bnb   = (const float*)d_in[10];
  char*  ws   = (char*)d_ws;
  float* out  = (float*)d_out;
  float* psum = (float*)(ws + OFF_PSUM);
  float* psq  = (float*)(ws + OFF_PSQ);
  float* aff  = (float*)(ws + OFF_AFF);

  prep_kernel<<<4096, 256, 0, stream>>>(theta, proto, fc1w, fc2w, ow, ws);

  (void)hipFuncSetAttribute((const void*)mega_kernel,
                            hipFuncAttributeMaxDynamicSharedMemorySize, SMEM_BYTES);
  mega_kernel<<<512, 512, SMEM_BYTES, stream>>>(x, ws, fc1b, fc2b, gamma, out, psum, psq);

  stats_kernel<<<512, 256, 0, stream>>>(psum, psq, bnw, bnb, aff);
  norm_kernel<<<2048, 256, 0, stream>>>(out, aff);
}

// Round 5
// 208.564 us; speedup vs baseline: 1.2088x; 1.1891x over previous
//
#include <hip/hip_runtime.h>

#define DI __device__ __forceinline__

using bf16x8 = __attribute__((ext_vector_type(8))) __bf16;
using bf16x4 = __attribute__((ext_vector_type(4))) __bf16;
using f32x4  = __attribute__((ext_vector_type(4))) float;

typedef unsigned short u16;
typedef unsigned int   u32;

static constexpr float SM_SCALE = 0.0625f;     // 1/sqrt(FEAT=256)
static constexpr float LAMBD    = 1.0f / 512.0f;

// ---------------- workspace byte offsets ----------------
static constexpr size_t OFF_THETA  = 0;         // bf16 [256][512]
static constexpr size_t OFF_PROTOT = 262144;    // bf16 [512][256]  (proto^T)
static constexpr size_t OFF_PROTO  = 524288;    // bf16 [256][512]
static constexpr size_t OFF_FC1    = 786432;    // bf16 [512][512]
static constexpr size_t OFF_FC2    = 1310720;   // bf16 [512][512]
static constexpr size_t OFF_O      = 1835008;   // bf16 [512][256]
static constexpr size_t OFF_PSUM   = 2097152;   // f32 [512 ch][512 blk]
static constexpr size_t OFF_PSQ    = 3145728;   // f32 [512 ch][512 blk]
static constexpr size_t OFF_AFF    = 4194304;   // f32 [512][2] (scale, shift)

// ---------------- LDS: two 32 KiB A-windows + reduce scratch ----------------
static constexpr int AB0 = 0;        // [64 rows][256 k] bf16, pitch 512B, swizzled
static constexpr int AB1 = 32768;    // k/col window 256..511
static constexpr int SCR = 65536;    // 2x2048 rrb + 2x256 rfb
static constexpr int SMEM_BYTES = 70144;

DI u16 f2b(float f) {
  union { float f; u32 u; } c; c.f = f;
  u32 r = c.u + 0x7FFFu + ((c.u >> 16) & 1u);   // RNE
  return (u16)(r >> 16);
}

// ---------------- prep: weights f32 -> bf16 (+ proto transpose) ----------------
__global__ __launch_bounds__(256) void prep_kernel(
    const float* __restrict__ theta, const float* __restrict__ proto,
    const float* __restrict__ fc1,   const float* __restrict__ fc2,
    const float* __restrict__ ow,    char* __restrict__ ws)
{
  u16* w_theta  = (u16*)(ws + OFF_THETA);
  u16* w_protoT = (u16*)(ws + OFF_PROTOT);
  u16* w_proto  = (u16*)(ws + OFF_PROTO);
  u16* w_fc1    = (u16*)(ws + OFF_FC1);
  u16* w_fc2    = (u16*)(ws + OFF_FC2);
  u16* w_o      = (u16*)(ws + OFF_O);
  for (int i = blockIdx.x * blockDim.x + threadIdx.x; i < 1048576;
       i += gridDim.x * blockDim.x) {
    if (i < 131072) { w_theta[i] = f2b(theta[i]); }
    else if (i < 262144) { int j = i - 131072; int k = j >> 8, f = j & 255;
                           w_protoT[j] = f2b(proto[f * 512 + k]); }
    else if (i < 393216) { int j = i - 262144; w_proto[j] = f2b(proto[j]); }
    else if (i < 655360) { int j = i - 393216; w_fc1[j] = f2b(fc1[j]); }
    else if (i < 917504) { int j = i - 655360; w_fc2[j] = f2b(fc2[j]); }
    else                 { int j = i - 917504; w_o[j]   = f2b(ow[j]); }
  }
}

// ---------------- barrier: lgkm drain only (global loads stay in flight) ----------
DI void bar() {
  asm volatile("s_waitcnt lgkmcnt(0)" ::: "memory");
  __builtin_amdgcn_s_barrier();
}

// ---------------- LDS fragment access: [row][k] bf16, pitch 512B, swizzled ----------
DI bf16x8 ld_frag(const char* base, int row, int kbyte) {
  return *(const bf16x8*)(base + row * 512 + (kbyte ^ ((row & 7) << 4)));
}

// ---------------- K=256-window GEMM, B direct from global (L2), reg dbuf ----------
// acc[4 rowtiles][CT coltiles] += A_win[64][256] @ W[col0+cols][kw0..kw0+256]
template<int W, int CT>
DI void gemm_win(f32x4 (&acc)[4][CT], const char* awin,
                 const __bf16* __restrict__ wbase, int col0, int kw0,
                 int w, int l) {
  const int g  = l >> 4;
  const int lr = l & 15;
  const __bf16* wp[CT];
  #pragma unroll
  for (int j = 0; j < CT; ++j)
    wp[j] = wbase + (size_t)(col0 + ((w + 8 * j) << 4) + lr) * W + kw0 + g * 8;
  bf16x8 bc[CT];
  #pragma unroll
  for (int j = 0; j < CT; ++j) bc[j] = *(const bf16x8*)wp[j];
  #pragma unroll
  for (int kk = 0; kk < 8; ++kk) {
    bf16x8 af[4];
    #pragma unroll
    for (int r0 = 0; r0 < 4; ++r0)
      af[r0] = ld_frag(awin, r0 * 16 + lr, kk * 64 + g * 16);
    bf16x8 bn[CT];
    if (kk < 7) {
      #pragma unroll
      for (int j = 0; j < CT; ++j) bn[j] = *(const bf16x8*)(wp[j] + (kk + 1) * 32);
    }
    #pragma unroll
    for (int j = 0; j < CT; ++j)
      #pragma unroll
      for (int r0 = 0; r0 < 4; ++r0)
        acc[r0][j] = __builtin_amdgcn_mfma_f32_16x16x32_bf16(af[r0], bc[j], acc[r0][j], 0, 0, 0);
    if (kk < 7) {
      #pragma unroll
      for (int j = 0; j < CT; ++j) bc[j] = bn[j];
    }
  }
}

// ---------------- fragment stores to a 256-wide A-window (swizzled) -------
template<int CT>
DI void store_f32(char* aw, const f32x4 (&v)[4][CT], int w, int l) {
  #pragma unroll
  for (int j = 0; j < CT; ++j) {
    const int col = (w + 8 * j) * 16 + (l & 15);
    #pragma unroll
    for (int r0 = 0; r0 < 4; ++r0)
      #pragma unroll
      for (int rr = 0; rr < 4; ++rr) {
        const int row = r0 * 16 + (l >> 4) * 4 + rr;
        *(__bf16*)(aw + row * 512 + ((col * 2) ^ ((row & 7) << 4))) = (__bf16)v[r0][j][rr];
      }
  }
}
// store two coltiles v[r0][jb+0..1] of a [4][4] bf16 fragment set
DI void store_pair(char* aw, const bf16x4 (&v)[4][4], int jb, int w, int l) {
  #pragma unroll
  for (int j = 0; j < 2; ++j) {
    const int col = (w + 8 * j) * 16 + (l & 15);
    #pragma unroll
    for (int r0 = 0; r0 < 4; ++r0)
      #pragma unroll
      for (int rr = 0; rr < 4; ++rr) {
        const int row = r0 * 16 + (l >> 4) * 4 + rr;
        *(__bf16*)(aw + row * 512 + ((col * 2) ^ ((row & 7) << 4))) = v[r0][jb + j][rr];
      }
  }
}
DI void store_pair2(char* aw, const bf16x4 (&v)[4][2], int w, int l) {
  #pragma unroll
  for (int j = 0; j < 2; ++j) {
    const int col = (w + 8 * j) * 16 + (l & 15);
    #pragma unroll
    for (int r0 = 0; r0 < 4; ++r0)
      #pragma unroll
      for (int rr = 0; rr < 4; ++rr) {
        const int row = r0 * 16 + (l >> 4) * 4 + rr;
        *(__bf16*)(aw + row * 512 + ((col * 2) ^ ((row & 7) << 4))) = v[r0][j][rr];
      }
  }
}

DI float red16(float v) {
  #pragma unroll
  for (int s = 1; s < 16; s <<= 1) v += __shfl_xor(v, s, 64);
  return v;
}

// cross-wave per-row sum through SCR
DI void row_round(char* smem, int round, float (&part)[4][4], float (&res)[4][4],
                  int w, int l, int tid) {
  float* rrb = (float*)(smem + SCR + round * 2048);
  float* rfb = (float*)(smem + SCR + 4096 + round * 256);
  const int g = l >> 4;
  if ((l & 15) == 0) {
    #pragma unroll
    for (int r0 = 0; r0 < 4; ++r0)
      #pragma unroll
      for (int rr = 0; rr < 4; ++rr)
        rrb[(r0 * 16 + g * 4 + rr) * 8 + w] = part[r0][rr];
  }
  bar();
  if (tid < 64) {
    float m = 0.0f;
    #pragma unroll
    for (int q = 0; q < 8; ++q) m += rrb[tid * 8 + q];
    rfb[tid] = m;
  }
  bar();
  #pragma unroll
  for (int r0 = 0; r0 < 4; ++r0)
    #pragma unroll
    for (int rr = 0; rr < 4; ++rr)
      res[r0][rr] = rfb[r0 * 16 + g * 4 + rr];
}

// ---------------- mega: fused chain for 64 pixel-rows per block ----------------
__global__ __launch_bounds__(512, 4) void mega_kernel(
    const float* __restrict__ x, const char* __restrict__ ws,
    const float* __restrict__ fc1b, const float* __restrict__ fc2b,
    const float* __restrict__ gammap, float* __restrict__ out,
    float* __restrict__ psum, float* __restrict__ psq)
{
  extern __shared__ __align__(16) char smem[];
  const int tid = threadIdx.x;
  const int w   = tid >> 6;
  const int l   = tid & 63;
  const int bid = blockIdx.x;
  const int m0  = bid << 6;
  const int n   = m0 >> 12;
  const int p0  = m0 & 4095;

  const __bf16* w_theta  = (const __bf16*)(ws + OFF_THETA);
  const __bf16* w_protoT = (const __bf16*)(ws + OFF_PROTOT);
  const __bf16* w_proto  = (const __bf16*)(ws + OFF_PROTO);
  const __bf16* w_fc1    = (const __bf16*)(ws + OFF_FC1);
  const __bf16* w_fc2    = (const __bf16*)(ws + OFF_FC2);
  const __bf16* w_o      = (const __bf16*)(ws + OFF_O);

  char* ab0 = smem + AB0;
  char* ab1 = smem + AB1;

  const f32x4 zz = {0.f, 0.f, 0.f, 0.f};

  // ---- stage A: Q[64][256] = X[64][512] @ theta^T (channel windows of 256)
  f32x4 accq[4][2];
  #pragma unroll
  for (int a = 0; a < 4; ++a) { accq[a][0] = zz; accq[a][1] = zz; }
  #pragma unroll
  for (int ah = 0; ah < 2; ++ah) {
    bar();
    #pragma unroll
    for (int q = 0; q < 4; ++q) {
      const int cl = q * 64 + (tid >> 3);
      const int c  = ah * 256 + cl;
      const int j0 = (tid & 7) * 8;
      const float* xp = x + ((size_t)(n * 512 + c)) * 4096 + (size_t)(p0 + j0);
      f32x4 v0 = *(const f32x4*)xp;
      f32x4 v1 = *(const f32x4*)(xp + 4);
      #pragma unroll
      for (int i = 0; i < 8; ++i) {
        const float f = (i < 4) ? v0[i] : v1[i - 4];
        const int row = j0 + i;
        *(__bf16*)(ab0 + row * 512 + ((cl * 2) ^ ((row & 7) << 4))) = (__bf16)f;
      }
    }
    bar();
    gemm_win<512, 2>(accq, ab0, w_theta, 0, ah * 256, w, l);
  }

  // ---- Q -> AB0 (bf16)
  bar();
  store_f32<2>(ab0, accq, w, l);
  bar();

  // ---- stage B+C: logits halves -> exp (no max-sub; scaled logits ~N(0,<1), f32-safe)
  bf16x4 pe[4][4];              // e-values, bf16
  float  se[4][4];              // per-thread partial row sums of e
  #pragma unroll
  for (int r0 = 0; r0 < 4; ++r0)
    #pragma unroll
    for (int rr = 0; rr < 4; ++rr) se[r0][rr] = 0.f;
  #pragma unroll
  for (int h = 0; h < 2; ++h) {
    f32x4 accB[4][2];
    #pragma unroll
    for (int a = 0; a < 4; ++a) { accB[a][0] = zz; accB[a][1] = zz; }
    gemm_win<256, 2>(accB, ab0, w_protoT, h * 256, 0, w, l);
    #pragma unroll
    for (int r0 = 0; r0 < 4; ++r0)
      #pragma unroll
      for (int j = 0; j < 2; ++j)
        #pragma unroll
        for (int rr = 0; rr < 4; ++rr) {
          const float e = __expf(accB[r0][j][rr] * SM_SCALE);
          pe[r0][2 * h + j][rr] = (__bf16)e;
          se[r0][rr] += e;
        }
  }
  {
    float rres[4][4];
    #pragma unroll
    for (int r0 = 0; r0 < 4; ++r0)
      #pragma unroll
      for (int rr = 0; rr < 4; ++rr) se[r0][rr] = red16(se[r0][rr]);
    row_round(smem, 0, se, rres, w, l, tid);
    // hard-shrink on s = e/E; accumulate L1
    #pragma unroll
    for (int r0 = 0; r0 < 4; ++r0)
      #pragma unroll
      for (int rr = 0; rr < 4; ++rr) {
        const float rinv = 1.0f / rres[r0][rr];
        float s2 = 0.f;
        #pragma unroll
        for (int ft = 0; ft < 4; ++ft) {
          const float s = (float)pe[r0][ft][rr] * rinv;
          const float t = s - LAMBD;
          const float a = __fdividef(fmaxf(t, 0.f) * s, fabsf(t) + 1e-12f);
          pe[r0][ft][rr] = (__bf16)a;
          s2 += a;
        }
        se[r0][rr] = red16(s2);
      }
    row_round(smem, 1, se, rres, w, l, tid);
    #pragma unroll
    for (int r0 = 0; r0 < 4; ++r0)
      #pragma unroll
      for (int rr = 0; rr < 4; ++rr) {
        const float rinv = 1.0f / (rres[r0][rr] + 1e-12f);
        #pragma unroll
        for (int ft = 0; ft < 4; ++ft)
          pe[r0][ft][rr] = (__bf16)((float)pe[r0][ft][rr] * rinv);
      }
  }
  // pe now holds A1 (attn) in bf16 regs

  // ---- A1 -> AB0 (cols 0..255) + AB1 (cols 256..511)
  bar();
  store_pair(ab0, pe, 0, w, l);
  store_pair(ab1, pe, 2, w, l);
  bar();

  // ---- stage D: R = relu(A1 @ fc1^T + b1), zero interior barriers
  bf16x4 prb[2][4][2];
  #pragma unroll
  for (int rh = 0; rh < 2; ++rh) {
    f32x4 accd[4][2];
    #pragma unroll
    for (int a = 0; a < 4; ++a) { accd[a][0] = zz; accd[a][1] = zz; }
    gemm_win<512, 2>(accd, ab0, w_fc1, rh * 256, 0,   w, l);
    gemm_win<512, 2>(accd, ab1, w_fc1, rh * 256, 256, w, l);
    #pragma unroll
    for (int j = 0; j < 2; ++j) {
      const float b1 = fc1b[rh * 256 + (w + 8 * j) * 16 + (l & 15)];
      #pragma unroll
      for (int r0 = 0; r0 < 4; ++r0)
        #pragma unroll
        for (int rr = 0; rr < 4; ++rr)
          prb[rh][r0][j][rr] = (__bf16)fmaxf(accd[r0][j][rr] + b1, 0.f);
    }
  }

  // ---- R -> AB0/AB1
  bar();
  store_pair2(ab0, prb[0], w, l);
  store_pair2(ab1, prb[1], w, l);
  bar();

  // ---- stage E: A2 = A1 + R @ fc2^T + b2 (acc init from pe + b2)
  bf16x4 pab[4][4];
  #pragma unroll
  for (int ch = 0; ch < 2; ++ch) {
    f32x4 acce[4][2];
    #pragma unroll
    for (int jj = 0; jj < 2; ++jj) {
      const float b2 = fc2b[ch * 256 + (w + 8 * jj) * 16 + (l & 15)];
      #pragma unroll
      for (int r0 = 0; r0 < 4; ++r0)
        #pragma unroll
        for (int rr = 0; rr < 4; ++rr)
          acce[r0][jj][rr] = (float)pe[r0][2 * ch + jj][rr] + b2;
    }
    gemm_win<512, 2>(acce, ab0, w_fc2, ch * 256, 0,   w, l);
    gemm_win<512, 2>(acce, ab1, w_fc2, ch * 256, 256, w, l);
    #pragma unroll
    for (int r0 = 0; r0 < 4; ++r0)
      #pragma unroll
      for (int jj = 0; jj < 2; ++jj)
        #pragma unroll
        for (int rr = 0; rr < 4; ++rr) pab[r0][2 * ch + jj][rr] = (__bf16)acce[r0][jj][rr];
  }

  // ---- A2 -> AB0/AB1
  bar();
  store_pair(ab0, pab, 0, w, l);
  store_pair(ab1, pab, 2, w, l);
  bar();

  // ---- stage F: Rd[64][256] = A2 @ proto^T
  f32x4 accf[4][2];
  #pragma unroll
  for (int a = 0; a < 4; ++a) { accf[a][0] = zz; accf[a][1] = zz; }
  gemm_win<512, 2>(accf, ab0, w_proto, 0, 0,   w, l);
  gemm_win<512, 2>(accf, ab1, w_proto, 0, 256, w, l);

  // ---- Rd -> AB0
  bar();
  store_f32<2>(ab0, accf, w, l);
  bar();

  // ---- stage G (swapped operands): yT[512 c][64 m] = o_w @ Rd^T
  f32x4 accg[4][4];
  #pragma unroll
  for (int a = 0; a < 4; ++a)
    #pragma unroll
    for (int b = 0; b < 4; ++b) accg[a][b] = zz;
  {
    const int g  = l >> 4;
    const int lr = l & 15;
    const __bf16* wp[4];
    #pragma unroll
    for (int j = 0; j < 4; ++j)
      wp[j] = w_o + (size_t)(((w + 8 * j) << 4) + lr) * 256 + g * 8;
    #pragma unroll
    for (int kk = 0; kk < 8; ++kk) {
      bf16x8 of[4];
      #pragma unroll
      for (int j = 0; j < 4; ++j) of[j] = *(const bf16x8*)(wp[j] + kk * 32);
      #pragma unroll
      for (int ct = 0; ct < 4; ++ct) {
        bf16x8 rdv = ld_frag(ab0, ct * 16 + lr, kk * 64 + g * 16);
        #pragma unroll
        for (int j = 0; j < 4; ++j)
          accg[j][ct] = __builtin_amdgcn_mfma_f32_16x16x32_bf16(of[j], rdv, accg[j][ct], 0, 0, 0);
      }
    }
  }

  // ---- epilogue: y = gamma*conv + x (coalesced along p), BN partials per channel
  const float gmm = gammap[0];
  #pragma unroll
  for (int j = 0; j < 4; ++j) {
    #pragma unroll
    for (int rr = 0; rr < 4; ++rr) {
      const int c = (w + 8 * j) * 16 + (l >> 4) * 4 + rr;
      const size_t base = ((size_t)(n * 512 + c)) * 4096 + (size_t)p0;
      float sy = 0.f, sq = 0.f;
      #pragma unroll
      for (int ct = 0; ct < 4; ++ct) {
        const int ml = ct * 16 + (l & 15);
        const float y = gmm * accg[j][ct][rr] + x[base + ml];
        out[base + ml] = y;
        sy += y; sq += y * y;
      }
      sy = red16(sy);
      sq = red16(sq);
      if ((l & 15) == 0) {
        psum[(size_t)c * 512 + bid] = sy;
        psq [(size_t)c * 512 + bid] = sq;
      }
    }
  }
}

// ---------------- BN stats ----------------
__global__ __launch_bounds__(256) void stats_kernel(
    const float* __restrict__ psum, const float* __restrict__ psq,
    const float* __restrict__ bnw,  const float* __restrict__ bnb,
    float* __restrict__ aff)
{
  const int c = blockIdx.x;
  const int t = threadIdx.x;
  float s = psum[(size_t)c * 512 + t] + psum[(size_t)c * 512 + t + 256];
  float q = psq [(size_t)c * 512 + t] + psq [(size_t)c * 512 + t + 256];
  #pragma unroll
  for (int sh = 1; sh < 64; sh <<= 1) {
    s += __shfl_xor(s, sh, 64);
    q += __shfl_xor(q, sh, 64);
  }
  __shared__ float ls[4], lq[4];
  const int wv = t >> 6;
  if ((t & 63) == 0) { ls[wv] = s; lq[wv] = q; }
  __syncthreads();
  if (t == 0) {
    const float S = ls[0] + ls[1] + ls[2] + ls[3];
    const float Q = lq[0] + lq[1] + lq[2] + lq[3];
    const float mean = S * (1.0f / 32768.0f);
    const float var  = Q * (1.0f / 32768.0f) - mean * mean;
    const float inv  = rsqrtf(var + 1e-5f);
    const float sc   = bnw[c] * inv;
    aff[2 * c]     = sc;
    aff[2 * c + 1] = bnb[c] - mean * sc;
  }
}

// ---------------- BN apply (full tensor: 4,194,304 f32x4) ----------------
__global__ __launch_bounds__(256) void norm_kernel(float* __restrict__ out,
                                                   const float* __restrict__ aff)
{
  f32x4* p = (f32x4*)out;
  for (int i = blockIdx.x * blockDim.x + threadIdx.x; i < 4194304;
       i += gridDim.x * blockDim.x) {
    const int c = (i >> 10) & 511;
    const float sc = aff[2 * c], sh = aff[2 * c + 1];
    f32x4 v = p[i];
    #pragma unroll
    for (int k = 0; k < 4; ++k) v[k] = v[k] * sc + sh;
    p[i] = v;
  }
}

extern "C" void kernel_launch(void* const* d_in, const int* in_sizes, int n_in,
                              void* d_out, int out_size, void* d_ws, size_t ws_size,
                              hipStream_t stream) {
  const float* x     = (const float*)d_in[0];
  const float* theta = (const float*)d_in[1];
  const float* proto = (const float*)d_in[2];
  const float* fc1w  = (const float*)d_in[3];
  const float* fc1b  = (const float*)d_in[4];
  const float* fc2w  = (const float*)d_in[5];
  const float* fc2b  = (const float*)d_in[6];
  const float* ow    = (const float*)d_in[7];
  const float* gamma = (const float*)d_in[8];
  const float* bnw   = (const float*)d_in[9];
  const float* bnb   = (const float*)d_in[10];
  char*  ws   = (char*)d_ws;
  float* out  = (float*)d_out;
  float* psum = (float*)(ws + OFF_PSUM);
  float* psq  = (float*)(ws + OFF_PSQ);
  float* aff  = (float*)(ws + OFF_AFF);

  prep_kernel<<<4096, 256, 0, stream>>>(theta, proto, fc1w, fc2w, ow, ws);

  (void)hipFuncSetAttribute((const void*)mega_kernel,
                            hipFuncAttributeMaxDynamicSharedMemorySize, SMEM_BYTES);
  mega_kernel<<<512, 512, SMEM_BYTES, stream>>>(x, ws, fc1b, fc2b, gamma, out, psum, psq);

  stats_kernel<<<512, 256, 0, stream>>>(psum, psq, bnw, bnb, aff);
  norm_kernel<<<2048, 256, 0, stream>>>(out, aff);
}